// Round 3
// baseline (6329.535 us; speedup 1.0000x reference)
//
#include <hip/hip_runtime.h>
#include <stdint.h>

typedef __attribute__((ext_vector_type(8))) short short8;
typedef __attribute__((ext_vector_type(4))) float f32x4;

constexpr int cB = 32, cT = 512, cD = 512, cH = 512;
constexpr int cKI = 6 * cH;   // 3072
constexpr int NWG = 32;
constexpr int THR = 320;
constexpr int LDW = 40;       // gemm LDS row pitch (shorts): 32 data + 8 pad
constexpr int HP  = 520;      // rec  LDS row pitch (shorts): 512 data + 8 pad

__device__ __forceinline__ float bf2f(unsigned short u) {
  union { unsigned int i; float f; } x; x.i = ((unsigned int)u) << 16; return x.f;
}
__device__ __forceinline__ unsigned short f2bf(float f) {
  union { float f; unsigned int i; } x; x.f = f;
  return (unsigned short)((x.i + 0x7fffu + ((x.i >> 16) & 1u)) >> 16);
}
__device__ __forceinline__ float sigm(float v) { return 1.0f / (1.0f + __expf(-v)); }
__device__ __forceinline__ float tanh_f(float v) { return 2.0f / (1.0f + __expf(-2.0f * v)) - 1.0f; }

// ---------------- Phase 1: pi[t][k][b] = x[b][t][:] . Wi[k][:] + bi[k] ----------------
// fp32 inputs, convert to bf16 during LDS staging; bf16 MFMA; bf16 pi out.
__global__ __launch_bounds__(256) void gemm_pi(
    const float* __restrict__ x,    // [B][T][D] fp32
    const float* __restrict__ Wi,   // [6H][D] fp32
    const float* __restrict__ bi,   // [6H] fp32
    unsigned short* __restrict__ pi)// [T][6H][B] bf16
{
  __shared__ __align__(16) unsigned short Ai[128 * LDW];
  __shared__ __align__(16) unsigned short Bi[128 * LDW];

  const int tid = threadIdx.x;
  const int lane = tid & 63;
  const int w = tid >> 6;
  const int wm = w & 1, wn = w >> 1;
  const int k0 = blockIdx.x * 128;
  const int n0 = blockIdx.y * 128;   // n = t*32 + b

  f32x4 acc[4][4];
  #pragma unroll
  for (int i = 0; i < 4; i++)
    #pragma unroll
    for (int j = 0; j < 4; j++) acc[i][j] = (f32x4){0.f, 0.f, 0.f, 0.f};

  for (int kk = 0; kk < cD; kk += 32) {
    __syncthreads();   // prior-iter LDS reads done before overwrite
    #pragma unroll
    for (int it = 0; it < 4; it++) {
      int idx = tid + it * 256;          // 1024 units: 128 rows x 8 float4-chunks
      int r = idx >> 3, ch = idx & 7;
      int na = n0 + r;
      int bb = na & 31, tt = na >> 5;
      float4 va = *(const float4*)(x + ((size_t)bb * cT + tt) * cD + kk + ch * 4);
      ushort4 pa; pa.x = f2bf(va.x); pa.y = f2bf(va.y); pa.z = f2bf(va.z); pa.w = f2bf(va.w);
      *(ushort4*)(Ai + r * LDW + ch * 4) = pa;
      float4 vb = *(const float4*)(Wi + (size_t)(k0 + r) * cD + kk + ch * 4);
      ushort4 pb; pb.x = f2bf(vb.x); pb.y = f2bf(vb.y); pb.z = f2bf(vb.z); pb.w = f2bf(vb.w);
      *(ushort4*)(Bi + r * LDW + ch * 4) = pb;
    }
    __syncthreads();

    short8 af[4], bfr[4];
    const int q = lane >> 4;
    #pragma unroll
    for (int mi = 0; mi < 4; mi++) {
      int m = wm * 64 + mi * 16 + (lane & 15);
      af[mi] = *(const short8*)(Ai + m * LDW + q * 8);
    }
    #pragma unroll
    for (int ni = 0; ni < 4; ni++) {
      int n = wn * 64 + ni * 16 + (lane & 15);
      bfr[ni] = *(const short8*)(Bi + n * LDW + q * 8);
    }
    #pragma unroll
    for (int mi = 0; mi < 4; mi++)
      #pragma unroll
      for (int ni = 0; ni < 4; ni++)
        acc[mi][ni] = __builtin_amdgcn_mfma_f32_16x16x32_bf16(af[mi], bfr[ni], acc[mi][ni], 0, 0, 0);
  }

  // Epilogue: +bias, pack 4 consecutive b (C rows = M dim) per uint2, store bf16.
  #pragma unroll
  for (int ni = 0; ni < 4; ni++) {
    int kl = wn * 64 + ni * 16 + (lane & 15);       // C col (N) -> Wi row
    float bv = bi[k0 + kl];
    #pragma unroll
    for (int mi = 0; mi < 4; mi++) {
      int nl = wm * 64 + mi * 16 + (lane >> 4) * 4; // C row (M) -> x row (t*32+b)
      int nb = n0 + nl;
      int b0 = nb & 31, tt = nb >> 5;
      f32x4 a = acc[mi][ni];
      unsigned short v0 = f2bf(a.x + bv), v1 = f2bf(a.y + bv);
      unsigned short v2 = f2bf(a.z + bv), v3 = f2bf(a.w + bv);
      uint2 pv; pv.x = (unsigned)v0 | ((unsigned)v1 << 16);
      pv.y = (unsigned)v2 | ((unsigned)v3 << 16);
      *(uint2*)(pi + ((size_t)tt * cKI + k0 + kl) * cB + b0) = pv;
    }
  }
}

// ---------------- grid barrier (monotonic counter, device scope) ----------------
__device__ __forceinline__ void gbar(int* bar, int target) {
  __threadfence();
  __syncthreads();
  if (threadIdx.x == 0) {
    __hip_atomic_fetch_add(bar, 1, __ATOMIC_ACQ_REL, __HIP_MEMORY_SCOPE_AGENT);
    while (__hip_atomic_load(bar, __ATOMIC_ACQUIRE, __HIP_MEMORY_SCOPE_AGENT) < target) {
      __builtin_amdgcn_s_sleep(1);
    }
  }
  __syncthreads();
  __threadfence();
}

// ---------------- Phase 2: persistent recurrent scan ----------------
// 32 WGs; WG i owns h-columns [16i,16i+16). Ws slice (80 rows x 512) resident in LDS (bf16).
__global__ __launch_bounds__(THR, 1) void lstm_rec(
    const unsigned short* __restrict__ pi,   // [T][6H][B] bf16
    const float* __restrict__ Ws,            // [5H][H] fp32
    const float* __restrict__ bs,            // [5H] fp32
    const int* __restrict__ lengths,         // [B]
    unsigned short* __restrict__ hbuf,       // [2][B][H] bf16
    int* __restrict__ bar,
    float* __restrict__ out)                 // ys[B][T][H], hT[B][H], cT[B][H] fp32
{
  __shared__ __align__(16) unsigned short ws_lds[80 * HP];   // 83.2 KB
  __shared__ __align__(16) unsigned short h_lds[32 * HP];    // 33.3 KB
  __shared__ __align__(16) float ps_lds[5 * 16 * 36];        // [gate][c][b pad 36]
  __shared__ __align__(16) float c_lds[16 * 32];             // [c][b]
  __shared__ float bs_lds[80];
  __shared__ int len_lds[32];

  const int tid = threadIdx.x;
  const int lane = tid & 63;
  const int w = tid >> 6;          // wave = gate (0..4)
  const int wg = blockIdx.x;
  const int ci0 = wg * 16;

  // preload Ws slice (once): LDS row r -> Ws[(r>>4)*H + ci0 + (r&15)][:], fp32->bf16
  for (int q = tid; q < 80 * 128; q += THR) {
    int r = q >> 7, ch = q & 127;
    int grow = (r >> 4) * cH + ci0 + (r & 15);
    float4 v = *(const float4*)(Ws + (size_t)grow * cH + ch * 4);
    ushort4 p; p.x = f2bf(v.x); p.y = f2bf(v.y); p.z = f2bf(v.z); p.w = f2bf(v.w);
    *(ushort4*)(ws_lds + r * HP + ch * 4) = p;
  }
  if (tid < 80) bs_lds[tid] = bs[(tid >> 4) * cH + ci0 + (tid & 15)];
  if (tid < cB) len_lds[tid] = lengths[tid];
  for (int q = tid; q < 16 * 32; q += THR) c_lds[q] = 0.0f;
  for (int e = tid; e < 512; e += THR) {                     // h0 = 0 (both buffers)
    hbuf[wg * 512 + e] = 0;
    hbuf[cB * cH + wg * 512 + e] = 0;
  }

  int target = NWG;
  gbar(bar, target);

  const int mc = lane & 15;
  const int kq = lane >> 4;
  const int brow = w * 16 + mc;

  for (int t = 0; t < cT; t++) {
    // stage full h into LDS (plain vector copies, bf16)
    const unsigned short* hsrc = hbuf + (size_t)(t & 1) * cB * cH;
    #pragma unroll
    for (int it = 0; it < 7; it++) {
      int idx = tid + it * THR;       // 2048 chunk-copies of 16B
      if (idx < 2048) {
        int r = idx >> 6, ch = idx & 63;
        uint4 v = *(const uint4*)(hsrc + r * cH + ch * 8);
        *(uint4*)(h_lds + r * HP + ch * 8) = v;
      }
    }
    __syncthreads();

    // wave w computes ps[:, gate w] : 32x16, K=512
    f32x4 acc0 = (f32x4){0.f,0.f,0.f,0.f}, acc1 = (f32x4){0.f,0.f,0.f,0.f};
    #pragma unroll
    for (int kt = 0; kt < 16; kt++) {
      int kc = kt * 4 + kq;
      short8 a0 = *(const short8*)(h_lds + mc * HP + kc * 8);
      short8 a1 = *(const short8*)(h_lds + (16 + mc) * HP + kc * 8);
      short8 bb = *(const short8*)(ws_lds + brow * HP + kc * 8);
      acc0 = __builtin_amdgcn_mfma_f32_16x16x32_bf16(a0, bb, acc0, 0, 0, 0);
      acc1 = __builtin_amdgcn_mfma_f32_16x16x32_bf16(a1, bb, acc1, 0, 0, 0);
    }
    {
      int r0 = kq * 4;   // C layout: col=lane&15 (=c), rows=(lane>>4)*4+reg (=b)
      *(f32x4*)(ps_lds + (w * 16 + mc) * 36 + r0) = acc0;
      *(f32x4*)(ps_lds + (w * 16 + mc) * 36 + r0 + 16) = acc1;
    }
    __syncthreads();

    // gates (fp32), y/h/c update
    const unsigned short* pit = pi + (size_t)t * cKI * cB;
    unsigned short* hdst = hbuf + (size_t)((t + 1) & 1) * cB * cH;
    #pragma unroll
    for (int u = 0; u < 2; u++) {
      int idx = tid + u * THR;
      if (idx < 512) {
        int b = idx & 31, c = idx >> 5;
        int col = ci0 + c;
        float a_i = bf2f(pit[(0 * cH + col) * cB + b]) + ps_lds[(0*16 + c)*36 + b] + bs_lds[0*16 + c];
        float a_f = bf2f(pit[(1 * cH + col) * cB + b]) + ps_lds[(1*16 + c)*36 + b] + bs_lds[1*16 + c];
        float a_g = bf2f(pit[(2 * cH + col) * cB + b]) + ps_lds[(2*16 + c)*36 + b] + bs_lds[2*16 + c];
        float a_o = bf2f(pit[(3 * cH + col) * cB + b]) + ps_lds[(3*16 + c)*36 + b] + bs_lds[3*16 + c];
        float a_r = bf2f(pit[(4 * cH + col) * cB + b]) + ps_lds[(4*16 + c)*36 + b] + bs_lds[4*16 + c];
        float p5  = bf2f(pit[(5 * cH + col) * cB + b]);
        float gi = sigm(a_i), gf = sigm(a_f), gg = tanh_f(a_g), go = sigm(a_o), gr = sigm(a_r);
        float cold = c_lds[c * 32 + b];
        float cn = gi * gg + gf * cold;
        float ov = go * tanh_f(cn);
        ov = gr * ov + (1.0f - gr) * p5;
        bool m = (t < len_lds[b]);
        float hold = bf2f(h_lds[b * HP + col]);
        float hn = m ? ov : hold;
        c_lds[c * 32 + b] = m ? cn : cold;
        hdst[b * cH + col] = f2bf(hn);
        out[((size_t)b * cT + t) * cH + col] = m ? ov : 0.0f;
      }
    }
    target += NWG;
    gbar(bar, target);
  }

  // finals: hT from hbuf[T&1] (own column slice), cT from local c state (fp32)
  const unsigned short* hfin = hbuf + (size_t)(cT & 1) * cB * cH;
  #pragma unroll
  for (int u = 0; u < 2; u++) {
    int idx = tid + u * THR;
    if (idx < 512) {
      int b = idx & 31, c = idx >> 5;
      int col = ci0 + c;
      out[(size_t)cB * cT * cH + (size_t)b * cH + col] = bf2f(hfin[b * cH + col]);
      out[(size_t)cB * cT * cH + (size_t)cB * cH + (size_t)b * cH + col] = c_lds[c * 32 + b];
    }
  }
}

extern "C" void kernel_launch(void* const* d_in, const int* in_sizes, int n_in,
                              void* d_out, int out_size, void* d_ws, size_t ws_size,
                              hipStream_t stream) {
  const float* x       = (const float*)d_in[0];
  const int* lengths   = (const int*)d_in[1];
  const float* Wi      = (const float*)d_in[2];
  const float* bi      = (const float*)d_in[3];
  const float* Ws      = (const float*)d_in[4];
  const float* bs      = (const float*)d_in[5];
  float* out = (float*)d_out;

  char* ws = (char*)d_ws;
  int* bar = (int*)ws;                                      // barrier counter
  unsigned short* hbuf = (unsigned short*)(ws + 512);       // 2*32*512*2 = 64KB
  unsigned short* pi   = (unsigned short*)(ws + (1 << 20)); // [512][3072][32] bf16 = 100.7MB

  hipMemsetAsync(bar, 0, 256, stream);
  dim3 grid1(cKI / 128, (cB * cT) / 128);   // 24 x 128 tiles
  gemm_pi<<<grid1, 256, 0, stream>>>(x, Wi, bi, pi);
  lstm_rec<<<NWG, THR, 0, stream>>>(pi, Ws, bs, lengths, hbuf, bar, out);
}

// Round 5
// 2165.077 us; speedup vs baseline: 2.9235x; 2.9235x over previous
//
#include <hip/hip_runtime.h>
#include <stdint.h>

typedef __attribute__((ext_vector_type(8))) short short8;
typedef __attribute__((ext_vector_type(4))) float f32x4;
typedef unsigned long long u64;

constexpr int cB = 32, cT = 512, cD = 512, cH = 512;
constexpr int cKI = 6 * cH;   // 3072
constexpr int NWG = 32;
constexpr int THR = 320;
constexpr int LDW = 40;       // gemm LDS row pitch (shorts)
constexpr int HP  = 520;      // rec LDS row pitch (shorts)
constexpr int RNG = 3;        // pi prefetch ring depth

__device__ __forceinline__ float bf2f(unsigned short u) {
  union { unsigned int i; float f; } x; x.i = ((unsigned int)u) << 16; return x.f;
}
__device__ __forceinline__ unsigned short f2bf(float f) {
  union { float f; unsigned int i; } x; x.f = f;
  return (unsigned short)((x.i + 0x7fffu + ((x.i >> 16) & 1u)) >> 16);
}
__device__ __forceinline__ float sigm(float v) { return 1.0f / (1.0f + __expf(-v)); }
__device__ __forceinline__ float tanh_f(float v) { return 2.0f / (1.0f + __expf(-2.0f * v)) - 1.0f; }

// ---------------- Phase 1: pi[t][k][b] = x[b][t][:] . Wi[k][:] + bi[k] ----------------
__global__ __launch_bounds__(256) void gemm_pi(
    const float* __restrict__ x,    // [B][T][D] fp32
    const float* __restrict__ Wi,   // [6H][D] fp32
    const float* __restrict__ bi,   // [6H] fp32
    unsigned short* __restrict__ pi)// [T][6H][B] bf16
{
  __shared__ __align__(16) unsigned short Ai[128 * LDW];
  __shared__ __align__(16) unsigned short Bi[128 * LDW];

  const int tid = threadIdx.x;
  const int lane = tid & 63;
  const int w = tid >> 6;
  const int wm = w & 1, wn = w >> 1;
  const int k0 = blockIdx.x * 128;
  const int n0 = blockIdx.y * 128;   // n = t*32 + b

  f32x4 acc[4][4];
  #pragma unroll
  for (int i = 0; i < 4; i++)
    #pragma unroll
    for (int j = 0; j < 4; j++) acc[i][j] = (f32x4){0.f, 0.f, 0.f, 0.f};

  for (int kk = 0; kk < cD; kk += 32) {
    __syncthreads();
    #pragma unroll
    for (int it = 0; it < 4; it++) {
      int idx = tid + it * 256;
      int r = idx >> 3, ch = idx & 7;
      int na = n0 + r;
      int bb = na & 31, tt = na >> 5;
      float4 va = *(const float4*)(x + ((size_t)bb * cT + tt) * cD + kk + ch * 4);
      ushort4 pa; pa.x = f2bf(va.x); pa.y = f2bf(va.y); pa.z = f2bf(va.z); pa.w = f2bf(va.w);
      *(ushort4*)(Ai + r * LDW + ch * 4) = pa;
      float4 vb = *(const float4*)(Wi + (size_t)(k0 + r) * cD + kk + ch * 4);
      ushort4 pb; pb.x = f2bf(vb.x); pb.y = f2bf(vb.y); pb.z = f2bf(vb.z); pb.w = f2bf(vb.w);
      *(ushort4*)(Bi + r * LDW + ch * 4) = pb;
    }
    __syncthreads();

    short8 af[4], bfr[4];
    const int q = lane >> 4;
    #pragma unroll
    for (int mi = 0; mi < 4; mi++) {
      int m = wm * 64 + mi * 16 + (lane & 15);
      af[mi] = *(const short8*)(Ai + m * LDW + q * 8);
    }
    #pragma unroll
    for (int ni = 0; ni < 4; ni++) {
      int n = wn * 64 + ni * 16 + (lane & 15);
      bfr[ni] = *(const short8*)(Bi + n * LDW + q * 8);
    }
    #pragma unroll
    for (int mi = 0; mi < 4; mi++)
      #pragma unroll
      for (int ni = 0; ni < 4; ni++)
        acc[mi][ni] = __builtin_amdgcn_mfma_f32_16x16x32_bf16(af[mi], bfr[ni], acc[mi][ni], 0, 0, 0);
  }

  #pragma unroll
  for (int ni = 0; ni < 4; ni++) {
    int kl = wn * 64 + ni * 16 + (lane & 15);
    float bv = bi[k0 + kl];
    #pragma unroll
    for (int mi = 0; mi < 4; mi++) {
      int nl = wm * 64 + mi * 16 + (lane >> 4) * 4;
      int nb = n0 + nl;
      int b0 = nb & 31, tt = nb >> 5;
      f32x4 a = acc[mi][ni];
      unsigned short v0 = f2bf(a.x + bv), v1 = f2bf(a.y + bv);
      unsigned short v2 = f2bf(a.z + bv), v3 = f2bf(a.w + bv);
      uint2 pv; pv.x = (unsigned)v0 | ((unsigned)v1 << 16);
      pv.y = (unsigned)v2 | ((unsigned)v3 << 16);
      *(uint2*)(pi + ((size_t)tt * cKI + k0 + kl) * cB + b0) = pv;
    }
  }
}

// ---------------- Phase 2: persistent recurrent scan (relaxed-atomic exchange) ----------------
__global__ __launch_bounds__(THR, 1) void lstm_rec(
    const unsigned short* __restrict__ pi,   // [T][6H][B] bf16
    const float* __restrict__ Ws,            // [5H][H] fp32
    const float* __restrict__ bs,            // [5H] fp32
    const int* __restrict__ lengths,         // [B]
    unsigned short* __restrict__ hbuf,       // [2][B][H] bf16 (coherent-path only)
    int* __restrict__ bar,
    float* __restrict__ out)                 // ys[B][T][H], hT[B][H], cT[B][H] fp32
{
  __shared__ __align__(16) unsigned short ws_lds[80 * HP];        // 83.2 KB
  __shared__ __align__(16) unsigned short h_lds[32 * HP];         // 33.3 KB
  __shared__ __align__(16) unsigned short piL[RNG * 6 * 16 * 32]; // 18.4 KB ring [slot][g][c][b]
  __shared__ __align__(16) float ps_lds[5 * 16 * 36];             // [gate][c][b pad]
  __shared__ __align__(16) float c_lds[16 * 32];                  // [c][b]
  __shared__ __align__(16) unsigned short hstg[16 * 32];          // [c][b]
  __shared__ float bs_lds[80];
  __shared__ int len_lds[32];

  const int tid = threadIdx.x;
  const int lane = tid & 63;
  const int w = tid >> 6;          // wave = gate (0..4)
  const int wg = blockIdx.x;
  const int ci0 = wg * 16;

  // Ws slice preload (once): LDS row r -> Ws[(r>>4)*H + ci0 + (r&15)][:]
  for (int q = tid; q < 80 * 128; q += THR) {
    int r = q >> 7, ch = q & 127;
    int grow = (r >> 4) * cH + ci0 + (r & 15);
    float4 v = *(const float4*)(Ws + (size_t)grow * cH + ch * 4);
    ushort4 p; p.x = f2bf(v.x); p.y = f2bf(v.y); p.z = f2bf(v.z); p.w = f2bf(v.w);
    *(ushort4*)(ws_lds + r * HP + ch * 4) = p;
  }
  if (tid < 80) bs_lds[tid] = bs[(tid >> 4) * cH + ci0 + (tid & 15)];
  if (tid < cB) len_lds[tid] = lengths[tid];
  for (int q = tid; q < 16 * 32; q += THR) c_lds[q] = 0.0f;
  for (int q = tid; q < 32 * HP / 4; q += THR) ((u64*)h_lds)[q] = 0ull;   // h0 = 0

  // prologue pi prefetch: t=0 -> slot0, t=1 -> slot1
  for (int s = 0; s < 2; s++) {
    const unsigned short* pit = pi + (size_t)s * cKI * cB;
    for (int j = tid; j < 384; j += THR) {
      int g = j >> 6, rem = j & 63, c = rem >> 2, q = rem & 3;
      uint4 v = *(const uint4*)(pit + ((size_t)g * cH + ci0 + c) * cB + q * 8);
      *(uint4*)(piL + s * 3072 + (g * 16 + c) * 32 + q * 8) = v;
    }
  }
  __syncthreads();

  int target = NWG;
  const int mc = lane & 15;
  const int kq = lane >> 4;
  const int brow = w * 16 + mc;

  for (int t = 0; t < cT; t++) {
    // (A) h staging loads via coherent path (skip t=0: LDS already zero)
    u64 hv[13];
    if (t > 0) {
      u64* hs = (u64*)(hbuf + (size_t)(t & 1) * cB * cH);
      #pragma unroll
      for (int k = 0; k < 13; k++) {
        int idx = tid + k * THR;
        if (idx < 4096)
          hv[k] = __hip_atomic_load(hs + idx, __ATOMIC_RELAXED, __HIP_MEMORY_SCOPE_AGENT);
      }
    }
    // (B) pi global loads for step t+2 (held in regs, LDS-written after MFMA)
    uint4 pv0, pv1;
    const bool pf = (t + 2) < cT;
    const int slot_w = (t + 2) % RNG;
    if (pf) {
      const unsigned short* pit = pi + (size_t)(t + 2) * cKI * cB;
      { int g = tid >> 6, rem = tid & 63, c = rem >> 2, q = rem & 3;
        pv0 = *(const uint4*)(pit + ((size_t)g * cH + ci0 + c) * cB + q * 8); }
      int j1 = tid + THR;
      if (j1 < 384) { int g = j1 >> 6, rem = j1 & 63, c = rem >> 2, q = rem & 3;
        pv1 = *(const uint4*)(pit + ((size_t)g * cH + ci0 + c) * cB + q * 8); }
    }
    // (C) write staged h into LDS
    if (t > 0) {
      #pragma unroll
      for (int k = 0; k < 13; k++) {
        int idx = tid + k * THR;
        if (idx < 4096) {
          int b = idx >> 7, ch = idx & 127;
          *(u64*)(h_lds + b * HP + ch * 4) = hv[k];
        }
      }
    }
    __syncthreads();

    // (D) MFMA: wave w computes ps[:, gate w] : 32x16, K=512
    f32x4 acc0 = (f32x4){0.f,0.f,0.f,0.f}, acc1 = (f32x4){0.f,0.f,0.f,0.f};
    #pragma unroll
    for (int kt = 0; kt < 16; kt++) {
      int kc = kt * 4 + kq;
      short8 a0 = *(const short8*)(h_lds + mc * HP + kc * 8);
      short8 a1 = *(const short8*)(h_lds + (16 + mc) * HP + kc * 8);
      short8 bb = *(const short8*)(ws_lds + brow * HP + kc * 8);
      acc0 = __builtin_amdgcn_mfma_f32_16x16x32_bf16(a0, bb, acc0, 0, 0, 0);
      acc1 = __builtin_amdgcn_mfma_f32_16x16x32_bf16(a1, bb, acc1, 0, 0, 0);
    }
    {
      int r0 = kq * 4;   // C layout: col=lane&15 (=c), rows=(lane>>4)*4+reg (=b)
      *(f32x4*)(ps_lds + (w * 16 + mc) * 36 + r0) = acc0;
      *(f32x4*)(ps_lds + (w * 16 + mc) * 36 + r0 + 16) = acc1;
    }
    // (E) pi ring LDS write for t+2 (loads have had (C)+(D) to land)
    if (pf) {
      { int g = tid >> 6, rem = tid & 63, c = rem >> 2, q = rem & 3;
        *(uint4*)(piL + slot_w * 3072 + (g * 16 + c) * 32 + q * 8) = pv0; }
      int j1 = tid + THR;
      if (j1 < 384) { int g = j1 >> 6, rem = j1 & 63, c = rem >> 2, q = rem & 3;
        *(uint4*)(piL + slot_w * 3072 + (g * 16 + c) * 32 + q * 8) = pv1; }
    }
    __syncthreads();

    // (F) gates (fp32)
    const unsigned short* pl = piL + (t % RNG) * 3072;
    #pragma unroll
    for (int u = 0; u < 2; u++) {
      int idx = tid + u * THR;
      if (idx < 512) {
        int b = idx & 31, c = idx >> 5;
        int col = ci0 + c;
        float a_i = bf2f(pl[(0*16 + c)*32 + b]) + ps_lds[(0*16 + c)*36 + b] + bs_lds[0*16 + c];
        float a_f = bf2f(pl[(1*16 + c)*32 + b]) + ps_lds[(1*16 + c)*36 + b] + bs_lds[1*16 + c];
        float a_g = bf2f(pl[(2*16 + c)*32 + b]) + ps_lds[(2*16 + c)*36 + b] + bs_lds[2*16 + c];
        float a_o = bf2f(pl[(3*16 + c)*32 + b]) + ps_lds[(3*16 + c)*36 + b] + bs_lds[3*16 + c];
        float a_r = bf2f(pl[(4*16 + c)*32 + b]) + ps_lds[(4*16 + c)*36 + b] + bs_lds[4*16 + c];
        float p5  = bf2f(pl[(5*16 + c)*32 + b]);
        float gi = sigm(a_i), gf = sigm(a_f), gg = tanh_f(a_g), go = sigm(a_o), gr = sigm(a_r);
        float cold = c_lds[c * 32 + b];
        float cn = gi * gg + gf * cold;
        float ov = go * tanh_f(cn);
        ov = gr * ov + (1.0f - gr) * p5;
        bool m = (t < len_lds[b]);
        float hold = bf2f(h_lds[b * HP + col]);
        float hn = m ? ov : hold;
        c_lds[c * 32 + b] = m ? cn : cold;
        hstg[c * 32 + b] = f2bf(hn);
        out[((size_t)b * cT + t) * cH + col] = m ? ov : 0.0f;
        if (t == cT - 1)
          out[(size_t)cB * cT * cH + (size_t)b * cH + col] = hn;   // hT
      }
    }
    __syncthreads();
    // (G) pack & publish h via coherent path (8B chunks); hbuf row = 128 u64
    if (tid < 128) {
      int b = tid >> 2, q = tid & 3;
      u64 pk = (u64)hstg[(q*4 + 0)*32 + b] | ((u64)hstg[(q*4 + 1)*32 + b] << 16)
             | ((u64)hstg[(q*4 + 2)*32 + b] << 32) | ((u64)hstg[(q*4 + 3)*32 + b] << 48);
      u64* hd = (u64*)(hbuf + (size_t)((t + 1) & 1) * cB * cH);
      __hip_atomic_store(hd + b * 128 + (ci0 >> 2) + q, pk, __ATOMIC_RELAXED, __HIP_MEMORY_SCOPE_AGENT);
    }
    // (H) grid barrier: syncthreads drains vmcnt (publishes h), relaxed arrive+spin
    __syncthreads();
    if (tid == 0) {
      __hip_atomic_fetch_add(bar, 1, __ATOMIC_RELAXED, __HIP_MEMORY_SCOPE_AGENT);
      while (__hip_atomic_load(bar, __ATOMIC_RELAXED, __HIP_MEMORY_SCOPE_AGENT) < target)
        __builtin_amdgcn_s_sleep(1);
    }
    target += NWG;
    __syncthreads();
  }

  // (I) cT from local c state
  #pragma unroll
  for (int u = 0; u < 2; u++) {
    int idx = tid + u * THR;
    if (idx < 512) {
      int b = idx & 31, c = idx >> 5;
      out[(size_t)cB * cT * cH + (size_t)cB * cH + (size_t)b * cH + ci0 + c] = c_lds[c * 32 + b];
    }
  }
}

extern "C" void kernel_launch(void* const* d_in, const int* in_sizes, int n_in,
                              void* d_out, int out_size, void* d_ws, size_t ws_size,
                              hipStream_t stream) {
  const float* x       = (const float*)d_in[0];
  const int* lengths   = (const int*)d_in[1];
  const float* Wi      = (const float*)d_in[2];
  const float* bi      = (const float*)d_in[3];
  const float* Ws      = (const float*)d_in[4];
  const float* bs      = (const float*)d_in[5];
  float* out = (float*)d_out;

  char* ws = (char*)d_ws;
  int* bar = (int*)ws;
  unsigned short* hbuf = (unsigned short*)(ws + 512);       // 2*32*512*2 = 64KB
  unsigned short* pi   = (unsigned short*)(ws + (1 << 20)); // [512][3072][32] bf16

  hipMemsetAsync(bar, 0, 256, stream);
  dim3 grid1(cKI / 128, (cB * cT) / 128);
  gemm_pi<<<grid1, 256, 0, stream>>>(x, Wi, bi, pi);
  lstm_rec<<<NWG, THR, 0, stream>>>(pi, Ws, bs, lengths, hbuf, bar, out);
}